// Round 3
// baseline (1715.428 us; speedup 1.0000x reference)
//
#include <hip/hip_runtime.h>
#include <math.h>

#define D_MODEL 1024
#define NH 16
#define DK 64
#define SEQ 2048
#define BATCH 2
#define MROWS (BATCH * SEQ)  // 4096
#define KR 16                // attention k-tile rows

typedef __attribute__((ext_vector_type(8))) short s8v;   // 8 bf16 (4 VGPRs) MFMA A/B frag
typedef __attribute__((ext_vector_type(4))) float f4v;   // MFMA C/D frag

// ---------------- helpers ----------------
__device__ __forceinline__ unsigned short bf16_rne(float x) {
    unsigned int u = __float_as_uint(x);
    unsigned int r = (u + 0x7FFFu + ((u >> 16) & 1u)) >> 16;
    return (unsigned short)r;
}
__device__ __forceinline__ float bf16f(unsigned short h) {
    return __uint_as_float(((unsigned int)h) << 16);
}
__device__ __forceinline__ void gll16(void* lds, const void* g) {
    // async global->LDS, 16B per lane, dest = wave-uniform base + lane*16
    __builtin_amdgcn_global_load_lds((const __attribute__((address_space(1))) unsigned int*)g,
                                     (__attribute__((address_space(3))) unsigned int*)lds,
                                     16, 0, 0);
}
__device__ __forceinline__ float dot4(float4 a, float4 b) {
    return fmaf(a.x, b.x, fmaf(a.y, b.y, fmaf(a.z, b.z, a.w * b.w)));
}

// ---------------- RoPE tables ----------------
__global__ __launch_bounds__(256) void rope_tab(float* __restrict__ ct, float* __restrict__ st) {
    int i = blockIdx.x * 256 + threadIdx.x;  // 0 .. SEQ*32-1
    int s = i >> 5, p = i & 31;
    double inv = exp(-((double)(2 * p) / 64.0) * 9.210340371976184);  // 10000^(-2p/64)
    double f = (double)s * inv;
    ct[i] = (float)cos(f);
    st[i] = (float)sin(f);
}

// ---------------- fp32 -> (bf16 hi, bf16 lo) row-major split ----------------
__global__ __launch_bounds__(256) void splitk(const float* __restrict__ src,
                                              unsigned short* __restrict__ hi,
                                              unsigned short* __restrict__ lo, int n4) {
    int i = blockIdx.x * 256 + threadIdx.x;
    const int stride = gridDim.x * 256;
    for (; i < n4; i += stride) {
        const float4 v = ((const float4*)src)[i];
        ushort4 h, l;
        h.x = bf16_rne(v.x); l.x = bf16_rne(v.x - bf16f(h.x));
        h.y = bf16_rne(v.y); l.y = bf16_rne(v.y - bf16f(h.y));
        h.z = bf16_rne(v.z); l.z = bf16_rne(v.z - bf16f(h.z));
        h.w = bf16_rne(v.w); l.w = bf16_rne(v.w - bf16f(h.w));
        ((ushort4*)hi)[i] = h;
        ((ushort4*)lo)[i] = l;
    }
}

// ---------------- W[k][n] -> WT[n][k] split-transpose (64x64 LDS tiles) ----------------
__global__ __launch_bounds__(256) void wsplit(const float* __restrict__ W,
                                              unsigned short* __restrict__ Th,
                                              unsigned short* __restrict__ Tl) {
    __shared__ float t[64][65];
    const int k0 = blockIdx.y * 64, n0 = blockIdx.x * 64;
    const int tid = threadIdx.x;
#pragma unroll
    for (int i = 0; i < 4; i++) {
        int u = tid + i * 256;                 // 0..1023
        int r = u >> 4, c = (u & 15) * 4;
        float4 v = *(const float4*)(W + (size_t)(k0 + r) * D_MODEL + n0 + c);
        t[r][c] = v.x; t[r][c + 1] = v.y; t[r][c + 2] = v.z; t[r][c + 3] = v.w;
    }
    __syncthreads();
#pragma unroll
    for (int i = 0; i < 4; i++) {
        int u = tid + i * 256;
        int nr = u >> 4, kc = (u & 15) * 4;
        ushort4 h, l;
        float x0 = t[kc + 0][nr], x1 = t[kc + 1][nr], x2 = t[kc + 2][nr], x3 = t[kc + 3][nr];
        h.x = bf16_rne(x0); l.x = bf16_rne(x0 - bf16f(h.x));
        h.y = bf16_rne(x1); l.y = bf16_rne(x1 - bf16f(h.y));
        h.z = bf16_rne(x2); l.z = bf16_rne(x2 - bf16f(h.z));
        h.w = bf16_rne(x3); l.w = bf16_rne(x3 - bf16f(h.w));
        *(ushort4*)(Th + (size_t)(n0 + nr) * D_MODEL + k0 + kc) = h;
        *(ushort4*)(Tl + (size_t)(n0 + nr) * D_MODEL + k0 + kc) = l;
    }
}

// ---------------- bf16x3 MFMA GEMM: C = A @ B^T' + bias  (B given as [n][k]) ----------------
// mode 0: z selects Q/K/V; RoPE fused for z<2; writes head-major [B,H,S,DK] fp32
// mode 1: plain write out[m][n] fp32
__global__ __launch_bounds__(256, 2) void gemm_b3(
    const unsigned short* __restrict__ Ah, const unsigned short* __restrict__ Al,
    const unsigned short* B0h, const unsigned short* B0l,
    const unsigned short* B1h, const unsigned short* B1l,
    const unsigned short* B2h, const unsigned short* B2l,
    const float* b0, const float* b1, const float* b2,
    float* o0, float* o1, float* o2,
    const float* __restrict__ ct, const float* __restrict__ st, int mode) {

    const int z = blockIdx.z;
    const unsigned short* Bh = (z == 0) ? B0h : ((z == 1) ? B1h : B2h);
    const unsigned short* Bl = (z == 0) ? B0l : ((z == 1) ? B1l : B2l);
    const float* bias = (z == 0) ? b0 : ((z == 1) ? b1 : b2);
    float* out = (z == 0) ? o0 : ((z == 1) ? o1 : o2);

    const int m0 = blockIdx.y * 128, n0 = blockIdx.x * 128;
    const int tid = threadIdx.x, w = tid >> 6, L = tid & 63;
    const int wr = w >> 1, wc = w & 1;

    __shared__ unsigned short sm[4][128][32];  // [Ah|Al|Bh|Bl], 128 rows x 32 bf16 (64B rows)

    f4v acc[4][4];
#pragma unroll
    for (int i = 0; i < 4; i++)
#pragma unroll
        for (int j = 0; j < 4; j++) acc[i][j] = (f4v){0.f, 0.f, 0.f, 0.f};

    const int fr = L & 15, kh = (L >> 4) * 8;

    for (int k0 = 0; k0 < D_MODEL; k0 += 32) {
#pragma unroll
        for (int t = 0; t < 2; t++) {
            const int i = w * 2 + t;                    // chunk 0..7 (16 rows each)
            const int row = i * 16 + (L >> 2);
            const size_t kof = (size_t)k0 + (L & 3) * 8;
            gll16(&sm[0][i * 16][0], Ah + (size_t)(m0 + row) * D_MODEL + kof);
            gll16(&sm[1][i * 16][0], Al + (size_t)(m0 + row) * D_MODEL + kof);
            gll16(&sm[2][i * 16][0], Bh + (size_t)(n0 + row) * D_MODEL + kof);
            gll16(&sm[3][i * 16][0], Bl + (size_t)(n0 + row) * D_MODEL + kof);
        }
        __syncthreads();

        s8v fah[4], fal[4], fbh[4], fbl[4];
#pragma unroll
        for (int mi = 0; mi < 4; mi++) {
            fah[mi] = *(const s8v*)&sm[0][wr * 64 + mi * 16 + fr][kh];
            fal[mi] = *(const s8v*)&sm[1][wr * 64 + mi * 16 + fr][kh];
        }
#pragma unroll
        for (int ni = 0; ni < 4; ni++) {
            fbh[ni] = *(const s8v*)&sm[2][wc * 64 + ni * 16 + fr][kh];
            fbl[ni] = *(const s8v*)&sm[3][wc * 64 + ni * 16 + fr][kh];
        }
#pragma unroll
        for (int mi = 0; mi < 4; mi++)
#pragma unroll
            for (int ni = 0; ni < 4; ni++) {
                acc[mi][ni] = __builtin_amdgcn_mfma_f32_16x16x32_bf16(fal[mi], fbh[ni], acc[mi][ni], 0, 0, 0);
                acc[mi][ni] = __builtin_amdgcn_mfma_f32_16x16x32_bf16(fah[mi], fbl[ni], acc[mi][ni], 0, 0, 0);
                acc[mi][ni] = __builtin_amdgcn_mfma_f32_16x16x32_bf16(fah[mi], fbh[ni], acc[mi][ni], 0, 0, 0);
            }
        __syncthreads();
    }

    // epilogue: C/D map (m89): col = lane&15, row = (lane>>4)*4 + reg
#pragma unroll
    for (int mi = 0; mi < 4; mi++)
#pragma unroll
        for (int ni = 0; ni < 4; ni++) {
            const int col = n0 + wc * 64 + ni * 16 + fr;
            const float bv = bias[col];
#pragma unroll
            for (int r = 0; r < 4; r++) {
                const int row = m0 + wr * 64 + mi * 16 + (L >> 4) * 4 + r;
                float v = acc[mi][ni][r] + bv;
                if (mode == 1) {
                    out[(size_t)row * D_MODEL + col] = v;
                } else {
                    const int b = row >> 11, s = row & (SEQ - 1);
                    const int h = col >> 6, d = col & 63;
                    float res;
                    if (z < 2) {  // RoPE: even/odd adjacent cols live in adjacent lanes
                        const float pr = __shfl_xor(v, 1, 64);
                        const int pp = d >> 1;
                        const float cv = ct[s * 32 + pp], sv = st[s * 32 + pp];
                        res = (L & 1) ? fmaf(pr, sv, v * cv) : fmaf(v, cv, -(pr * sv));
                    } else {
                        res = v;
                    }
                    out[((size_t)(b * NH + h) * SEQ + s) * DK + d] = res;
                }
            }
        }
}

// ---------------- flash attention: 1 wave per 64-query stripe, lane = query row ----------------
// Wave-private double-buffered LDS (no __syncthreads); counted vmcnt prefetch (T4).
__global__ __launch_bounds__(64, 2) void attn2(const float* __restrict__ Q,
                                               const float* __restrict__ K,
                                               const float* __restrict__ V,
                                               float* __restrict__ Ao) {
    __shared__ float Ks[2][KR][64];
    __shared__ float Vs[2][KR][64];
    const int bx = blockIdx.x;
    const int bh = bx & 31;            // b*NH + h
    const int p = 31 - (bx >> 5);      // stripe index; biggest stripes dispatch first
    const int L = threadIdx.x;         // lane = query within stripe
    const int q = p * 64 + L;
    const int b = bh >> 4, h = bh & 15;

    const float* Qp = Q + ((size_t)bh * SEQ + q) * DK;
    const float* Kp = K + (size_t)bh * SEQ * DK;
    const float* Vp = V + (size_t)bh * SEQ * DK;

    float4 qr4[16], o4[16];
#pragma unroll
    for (int j = 0; j < 16; j++) {
        qr4[j] = ((const float4*)Qp)[j];
        o4[j] = make_float4(0.f, 0.f, 0.f, 0.f);
    }
    float mx = -1e30f, lsum = 0.f;

    const int nkt = 4 * p + 4;  // KR-row tiles up to the causal diagonal
    const size_t lofs = (size_t)(L >> 4) * DK + (size_t)(L & 15) * 4;

    // prologue: stage tile 0 -> buf 0
#pragma unroll
    for (int c = 0; c < 4; c++) {
        gll16(&Ks[0][c * 4][0], Kp + lofs + (size_t)c * 4 * DK);
        gll16(&Vs[0][c * 4][0], Vp + lofs + (size_t)c * 4 * DK);
    }

    int cur = 0;
    for (int t = 0; t < nkt; t++) {
        if (t + 1 < nkt) {  // prefetch next tile into the other buffer
            const size_t g0 = (size_t)(t + 1) * KR * DK + lofs;
#pragma unroll
            for (int c = 0; c < 4; c++) {
                gll16(&Ks[cur ^ 1][c * 4][0], Kp + g0 + (size_t)c * 4 * DK);
                gll16(&Vs[cur ^ 1][c * 4][0], Vp + g0 + (size_t)c * 4 * DK);
            }
            asm volatile("s_waitcnt vmcnt(8)" ::: "memory");  // tile t complete; t+1 in flight
        } else {
            asm volatile("s_waitcnt vmcnt(0)" ::: "memory");
        }
        const int dk0 = t * KR - p * 64;  // k-local offset of this tile vs stripe base
#pragma unroll 4
        for (int kk = 0; kk < KR; kk++) {
            float s0 = 0.f, s1 = 0.f, s2 = 0.f, s3 = 0.f;
#pragma unroll
            for (int j = 0; j < 16; j += 4) {
                s0 += dot4(qr4[j + 0], *(const float4*)&Ks[cur][kk][j * 4 + 0]);
                s1 += dot4(qr4[j + 1], *(const float4*)&Ks[cur][kk][j * 4 + 4]);
                s2 += dot4(qr4[j + 2], *(const float4*)&Ks[cur][kk][j * 4 + 8]);
                s3 += dot4(qr4[j + 3], *(const float4*)&Ks[cur][kk][j * 4 + 12]);
            }
            float s = ((s0 + s1) + (s2 + s3)) * 0.125f;  // 1/sqrt(64)
            if (dk0 + kk > L) s = -1e30f;                // causal mask (no-op for interior tiles)
            if (s > mx + 8.f) {                          // defer-max rescale (T13, THR=8)
                const float c = __expf(mx - s);
                mx = s;
                lsum *= c;
#pragma unroll
                for (int j = 0; j < 16; j++) {
                    o4[j].x *= c; o4[j].y *= c; o4[j].z *= c; o4[j].w *= c;
                }
            }
            const float pw = __expf(s - mx);
            lsum += pw;
#pragma unroll
            for (int j = 0; j < 16; j++) {
                const float4 vv = *(const float4*)&Vs[cur][kk][j * 4];
                o4[j].x = fmaf(pw, vv.x, o4[j].x);
                o4[j].y = fmaf(pw, vv.y, o4[j].y);
                o4[j].z = fmaf(pw, vv.z, o4[j].z);
                o4[j].w = fmaf(pw, vv.w, o4[j].w);
            }
        }
        cur ^= 1;
    }

    const float inv = 1.0f / lsum;
    float* op = Ao + ((size_t)b * SEQ + q) * D_MODEL + h * DK;
#pragma unroll
    for (int j = 0; j < 16; j++) {
        float4 r = o4[j];
        r.x *= inv; r.y *= inv; r.z *= inv; r.w *= inv;
        ((float4*)op)[j] = r;
    }
}

// ---------------------------------------------------------------------------
extern "C" void kernel_launch(void* const* d_in, const int* in_sizes, int n_in,
                              void* d_out, int out_size, void* d_ws, size_t ws_size,
                              hipStream_t stream) {
    const float* x  = (const float*)d_in[0];
    const float* Wq = (const float*)d_in[1];
    const float* bq = (const float*)d_in[2];
    const float* Wk = (const float*)d_in[3];
    const float* bk = (const float*)d_in[4];
    const float* Wv = (const float*)d_in[5];
    const float* bv = (const float*)d_in[6];
    const float* Wo = (const float*)d_in[7];
    const float* bo = (const float*)d_in[8];
    float* out = (float*)d_out;

    char* wsb = (char*)d_ws;  // total footprint ~97 MB
    unsigned short* xh = (unsigned short*)(wsb);              // 8 MB (x split hi; later Ao hi)
    unsigned short* xl = (unsigned short*)(wsb + 8388608);    // 8 MB
    unsigned short* wt = (unsigned short*)(wsb + 16777216);   // 8 x 2 MB transposed W splits
    float* Qb = (float*)(wsb + 33554432);                     // [B,H,S,DK] fp32 16 MB
    float* Kb = (float*)(wsb + 50331648);
    float* Vb = (float*)(wsb + 67108864);
    float* Ao = (float*)(wsb + 83886080);                     // [B,S,D] fp32 16 MB
    float* ct = (float*)(wsb + 100663296);                    // [S][32]
    float* st = (float*)(wsb + 100925440);

    const size_t WSZ = 1048576;  // ushorts per W half-matrix

    rope_tab<<<256, 256, 0, stream>>>(ct, st);
    splitk<<<1024, 256, 0, stream>>>(x, xh, xl, (MROWS * D_MODEL) / 4);
    wsplit<<<dim3(16, 16), 256, 0, stream>>>(Wq, wt + 0 * WSZ, wt + 1 * WSZ);
    wsplit<<<dim3(16, 16), 256, 0, stream>>>(Wk, wt + 2 * WSZ, wt + 3 * WSZ);
    wsplit<<<dim3(16, 16), 256, 0, stream>>>(Wv, wt + 4 * WSZ, wt + 5 * WSZ);
    wsplit<<<dim3(16, 16), 256, 0, stream>>>(Wo, wt + 6 * WSZ, wt + 7 * WSZ);

    gemm_b3<<<dim3(8, 32, 3), 256, 0, stream>>>(xh, xl,
        wt + 0 * WSZ, wt + 1 * WSZ, wt + 2 * WSZ, wt + 3 * WSZ, wt + 4 * WSZ, wt + 5 * WSZ,
        bq, bk, bv, Qb, Kb, Vb, ct, st, 0);

    attn2<<<dim3(32 * 32), 64, 0, stream>>>(Qb, Kb, Vb, Ao);

    splitk<<<1024, 256, 0, stream>>>(Ao, xh, xl, (MROWS * D_MODEL) / 4);

    gemm_b3<<<dim3(8, 32, 1), 256, 0, stream>>>(xh, xl,
        wt + 6 * WSZ, wt + 7 * WSZ, wt + 6 * WSZ, wt + 7 * WSZ, wt + 6 * WSZ, wt + 7 * WSZ,
        bo, bo, bo, out, out, out, ct, st, 1);
}

// Round 7
// 386.945 us; speedup vs baseline: 4.4333x; 4.4333x over previous
//
#include <hip/hip_runtime.h>
#include <math.h>

#define D_MODEL 1024
#define NH 16
#define DK 64
#define SEQ 2048
#define BATCH 2
#define MROWS 4096

typedef __attribute__((ext_vector_type(8))) short s8v;   // 8 bf16 MFMA A/B frag
typedef __attribute__((ext_vector_type(4))) float f4v;   // MFMA C/D frag

// ---------------- helpers ----------------
__device__ __forceinline__ unsigned short bf16_rne(float x) {
    unsigned int u = __float_as_uint(x);
    unsigned int r = (u + 0x7FFFu + ((u >> 16) & 1u)) >> 16;
    return (unsigned short)r;
}
__device__ __forceinline__ float bf16f(unsigned short h) {
    return __uint_as_float(((unsigned int)h) << 16);
}
__device__ __forceinline__ void gll16(void* lds, const void* g) {
    // async global->LDS: LDS dest = wave-uniform base + lane*16; global src per-lane
    __builtin_amdgcn_global_load_lds((const __attribute__((address_space(1))) unsigned int*)g,
                                     (__attribute__((address_space(3))) unsigned int*)lds,
                                     16, 0, 0);
}

// ---------------- RoPE tables ----------------
__global__ __launch_bounds__(256) void rope_tab(float* __restrict__ ct, float* __restrict__ st) {
    int i = blockIdx.x * 256 + threadIdx.x;  // 0 .. SEQ*32-1
    int s = i >> 5, p = i & 31;
    double inv = exp(-((double)(2 * p) / 64.0) * 9.210340371976184);
    double f = (double)s * inv;
    ct[i] = (float)cos(f);
    st[i] = (float)sin(f);
}

// ---------------- fp32 -> (bf16 hi, bf16 lo) split ----------------
__global__ __launch_bounds__(256) void splitk(const float* __restrict__ src,
                                              unsigned short* __restrict__ hi,
                                              unsigned short* __restrict__ lo, int n4) {
    int i = blockIdx.x * 256 + threadIdx.x;
    const int stride = gridDim.x * 256;
    for (; i < n4; i += stride) {
        const float4 v = ((const float4*)src)[i];
        ushort4 h, l;
        h.x = bf16_rne(v.x); l.x = bf16_rne(v.x - bf16f(h.x));
        h.y = bf16_rne(v.y); l.y = bf16_rne(v.y - bf16f(h.y));
        h.z = bf16_rne(v.z); l.z = bf16_rne(v.z - bf16f(h.z));
        h.w = bf16_rne(v.w); l.w = bf16_rne(v.w - bf16f(h.w));
        ((ushort4*)hi)[i] = h;
        ((ushort4*)lo)[i] = l;
    }
}

// ---------------- W[k][n] -> WT[n][k] split-transpose ----------------
__global__ __launch_bounds__(256) void wsplit(const float* __restrict__ W,
                                              unsigned short* __restrict__ Th,
                                              unsigned short* __restrict__ Tl) {
    __shared__ float t[64][65];
    const int k0 = blockIdx.y * 64, n0 = blockIdx.x * 64;
    const int tid = threadIdx.x;
#pragma unroll
    for (int i = 0; i < 4; i++) {
        int u = tid + i * 256;
        int r = u >> 4, c = (u & 15) * 4;
        float4 v = *(const float4*)(W + (size_t)(k0 + r) * D_MODEL + n0 + c);
        t[r][c] = v.x; t[r][c + 1] = v.y; t[r][c + 2] = v.z; t[r][c + 3] = v.w;
    }
    __syncthreads();
#pragma unroll
    for (int i = 0; i < 4; i++) {
        int u = tid + i * 256;
        int nr = u >> 4, kc = (u & 15) * 4;
        ushort4 h, l;
        float x0 = t[kc + 0][nr], x1 = t[kc + 1][nr], x2 = t[kc + 2][nr], x3 = t[kc + 3][nr];
        h.x = bf16_rne(x0); l.x = bf16_rne(x0 - bf16f(h.x));
        h.y = bf16_rne(x1); l.y = bf16_rne(x1 - bf16f(h.y));
        h.z = bf16_rne(x2); l.z = bf16_rne(x2 - bf16f(h.z));
        h.w = bf16_rne(x3); l.w = bf16_rne(x3 - bf16f(h.w));
        *(ushort4*)(Th + (size_t)(n0 + nr) * D_MODEL + k0 + kc) = h;
        *(ushort4*)(Tl + (size_t)(n0 + nr) * D_MODEL + k0 + kc) = l;
    }
}

// ---------------- Vx [bh][s][64] bf16 -> VTx [bh][64][s] bf16 ----------------
__global__ __launch_bounds__(256) void vtrans(const unsigned short* __restrict__ Vh,
                                              unsigned short* __restrict__ VT) {
    __shared__ unsigned short t[64][65];
    const int bh = blockIdx.y, s0 = blockIdx.x * 64;
    const int tid = threadIdx.x;
    const int r = tid >> 2, c16 = (tid & 3) * 16;
#pragma unroll
    for (int i = 0; i < 2; i++) {
        s8v v = *(const s8v*)(Vh + ((size_t)bh * SEQ + s0 + r) * 64 + c16 + i * 8);
#pragma unroll
        for (int j = 0; j < 8; j++) t[r][c16 + i * 8 + j] = ((unsigned short*)&v)[j];
    }
    __syncthreads();
    const int d = tid >> 2, sc = (tid & 3) * 16;
#pragma unroll
    for (int i = 0; i < 2; i++) {
        s8v o;
#pragma unroll
        for (int j = 0; j < 8; j++) ((unsigned short*)&o)[j] = t[sc + i * 8 + j][d];
        *(s8v*)(VT + ((size_t)bh * 64 + d) * SEQ + s0 + sc + i * 8) = o;
    }
}

// ---------------- bf16x3 MFMA GEMM ----------------
// mode 0: z selects Q/K/V; RoPE fused for z<2; writes bf16 hi/lo pairs, [bh][s][d]
// mode 1: plain fp32 write out[m][n]
__global__ __launch_bounds__(256, 2) void gemm_b3(
    const unsigned short* __restrict__ Ah, const unsigned short* __restrict__ Al,
    const unsigned short* B0h, const unsigned short* B0l,
    const unsigned short* B1h, const unsigned short* B1l,
    const unsigned short* B2h, const unsigned short* B2l,
    const float* b0, const float* b1, const float* b2,
    float* out1,
    unsigned short* qh, unsigned short* ql, unsigned short* kh2, unsigned short* kl2,
    unsigned short* vh, unsigned short* vl,
    const float* __restrict__ ct, const float* __restrict__ st, int mode) {

    const int z = blockIdx.z;
    const unsigned short* Bh = (z == 0) ? B0h : ((z == 1) ? B1h : B2h);
    const unsigned short* Bl = (z == 0) ? B0l : ((z == 1) ? B1l : B2l);
    const float* bias = (z == 0) ? b0 : ((z == 1) ? b1 : b2);

    const int m0 = blockIdx.y * 128, n0 = blockIdx.x * 128;
    const int tid = threadIdx.x, w = tid >> 6, L = tid & 63;
    const int wr = w >> 1, wc = w & 1;

    __shared__ unsigned short sm[4][128][32];

    f4v acc[4][4];
#pragma unroll
    for (int i = 0; i < 4; i++)
#pragma unroll
        for (int j = 0; j < 4; j++) acc[i][j] = (f4v){0.f, 0.f, 0.f, 0.f};

    const int fr = L & 15, kh = (L >> 4) * 8;

    for (int k0 = 0; k0 < D_MODEL; k0 += 32) {
#pragma unroll
        for (int t = 0; t < 2; t++) {
            const int i = w * 2 + t;
            const int row = i * 16 + (L >> 2);
            const size_t kof = (size_t)k0 + (L & 3) * 8;
            gll16(&sm[0][i * 16][0], Ah + (size_t)(m0 + row) * D_MODEL + kof);
            gll16(&sm[1][i * 16][0], Al + (size_t)(m0 + row) * D_MODEL + kof);
            gll16(&sm[2][i * 16][0], Bh + (size_t)(n0 + row) * D_MODEL + kof);
            gll16(&sm[3][i * 16][0], Bl + (size_t)(n0 + row) * D_MODEL + kof);
        }
        __syncthreads();

        s8v fah[4], fal[4], fbh[4], fbl[4];
#pragma unroll
        for (int mi = 0; mi < 4; mi++) {
            fah[mi] = *(const s8v*)&sm[0][wr * 64 + mi * 16 + fr][kh];
            fal[mi] = *(const s8v*)&sm[1][wr * 64 + mi * 16 + fr][kh];
        }
#pragma unroll
        for (int ni = 0; ni < 4; ni++) {
            fbh[ni] = *(const s8v*)&sm[2][wc * 64 + ni * 16 + fr][kh];
            fbl[ni] = *(const s8v*)&sm[3][wc * 64 + ni * 16 + fr][kh];
        }
#pragma unroll
        for (int mi = 0; mi < 4; mi++)
#pragma unroll
            for (int ni = 0; ni < 4; ni++) {
                acc[mi][ni] = __builtin_amdgcn_mfma_f32_16x16x32_bf16(fal[mi], fbh[ni], acc[mi][ni], 0, 0, 0);
                acc[mi][ni] = __builtin_amdgcn_mfma_f32_16x16x32_bf16(fah[mi], fbl[ni], acc[mi][ni], 0, 0, 0);
                acc[mi][ni] = __builtin_amdgcn_mfma_f32_16x16x32_bf16(fah[mi], fbh[ni], acc[mi][ni], 0, 0, 0);
            }
        __syncthreads();
    }

    // epilogue: C/D map (session-verified on HW): col = lane&15, row = (lane>>4)*4 + reg
#pragma unroll
    for (int mi = 0; mi < 4; mi++)
#pragma unroll
        for (int ni = 0; ni < 4; ni++) {
            const int col = n0 + wc * 64 + ni * 16 + fr;
            const float bv = bias[col];
#pragma unroll
            for (int r = 0; r < 4; r++) {
                const int row = m0 + wr * 64 + mi * 16 + (L >> 4) * 4 + r;
                float v = acc[mi][ni][r] + bv;
                if (mode == 1) {
                    out1[(size_t)row * D_MODEL + col] = v;
                } else {
                    const int b = row >> 11, s = row & (SEQ - 1);
                    const int h = col >> 6, d = col & 63;
                    float res;
                    if (z < 2) {  // RoPE: even/odd adjacent cols are in adjacent lanes
                        const float pr = __shfl_xor(v, 1, 64);
                        const int pp = d >> 1;
                        const float cv = ct[s * 32 + pp], sv = st[s * 32 + pp];
                        res = (L & 1) ? fmaf(pr, sv, v * cv) : fmaf(v, cv, -(pr * sv));
                    } else {
                        res = v;
                    }
                    const size_t idx = ((size_t)(b * NH + h) * SEQ + s) * DK + d;
                    const unsigned short rh = bf16_rne(res);
                    const unsigned short rl = bf16_rne(res - bf16f(rh));
                    if (z == 0)      { qh[idx] = rh;  ql[idx] = rl; }
                    else if (z == 1) { kh2[idx] = rh; kl2[idx] = rl; }
                    else             { vh[idx] = rh;  vl[idx] = rl; }
                }
            }
        }
}

// ---------------- MFMA flash attention (full hi/lo numerics, PROVEN sync) ----------------
// Block = 4 waves = one 64-query stripe p of one (b,h). 32-kpos tiles, double-buffered:
//   __syncthreads(); stage(t+1 -> other buf); compute(buf t)
// The sync's vmcnt(0) drain guarantees tile t's global_load_lds completed (the same
// pattern gemm_b3 uses, replay-stable on this HW); stage(t+1) hides under compute(t).
// QK^T bf16x3, per-row online softmax (16-lane shfl reduce), P hi/lo in wave-private
// LDS, PV bf16x3.
__global__ __launch_bounds__(256, 2) void attn_mfma(
    const unsigned short* __restrict__ Qh, const unsigned short* __restrict__ Ql,
    const unsigned short* __restrict__ Kh, const unsigned short* __restrict__ Kl,
    const unsigned short* __restrict__ VTh, const unsigned short* __restrict__ VTl,
    float* __restrict__ Ao) {

    // LDS: 2 bufs x {Kh 4K | Kl 4K | VTh 4K | VTl 4K} + 4 waves x {Ph 1K | Pl 1K}
    __shared__ __align__(16) unsigned char LDS[40960];
    const int bx = blockIdx.x;
    const int bh = bx & 31;
    const int p = 31 - (bx >> 5);       // big stripes first
    const int tid = threadIdx.x;
    const int wq = tid >> 6, lane = tid & 63;
    const int b = bh >> 4, h = bh & 15;
    const int l15 = lane & 15, l4 = lane >> 4;

    // Q fragments: wave's 16 q-rows. A-frag: row = l15, k = c*32 + l4*8 + j
    const int qbase = p * 64 + wq * 16;
    s8v fqh[2], fql[2];
    {
        const size_t rowB = ((size_t)bh * SEQ + qbase + l15) * 128;  // 128B per row
        const int kof = l4 * 16;
        fqh[0] = *(const s8v*)((const char*)Qh + rowB + kof);
        fqh[1] = *(const s8v*)((const char*)Qh + rowB + kof + 64);
        fql[0] = *(const s8v*)((const char*)Ql + rowB + kof);
        fql[1] = *(const s8v*)((const char*)Ql + rowB + kof + 64);
    }

    f4v oacc[4];
#pragma unroll
    for (int i = 0; i < 4; i++) oacc[i] = (f4v){0.f, 0.f, 0.f, 0.f};
    float mrow[4] = {-1e30f, -1e30f, -1e30f, -1e30f};
    float lrow[4] = {0.f, 0.f, 0.f, 0.f};

    const int nkt = 2 * (p + 1);                  // 32-kpos tiles incl. diagonal
    unsigned char* Pw = LDS + 32768 + wq * 2048;  // wave-private: Ph @ +0, Pl @ +1024

    // stage one 32-kpos tile into buffer bb (16KB): each wave covers 1KB/array
    auto stage = [&](int t, unsigned char* bb) {
        {   // K hi/lo: rows of 128B (64 dims), XOR-swizzled via pre-swizzled source
            const int row = wq * 8 + (lane >> 3);
            const int off = (lane & 7) * 16;
            const int soff = off ^ ((row & 7) << 4);
            const size_t kB = ((size_t)bh * SEQ + (size_t)t * 32 + row) * 128 + soff;
            gll16(bb + 0    + wq * 1024, (const char*)Kh + kB);
            gll16(bb + 4096 + wq * 1024, (const char*)Kl + kB);
        }
        {   // V^T hi/lo: rows of 64B (d-major, 32 kpos), linear
            const int row = wq * 16 + (lane >> 2);
            const int off = (lane & 3) * 16;
            const size_t vB = (((size_t)bh * 64 + row) * SEQ + (size_t)t * 32) * 2 + off;
            gll16(bb + 8192  + wq * 1024, (const char*)VTh + vB);
            gll16(bb + 12288 + wq * 1024, (const char*)VTl + vB);
        }
    };

    stage(0, LDS);

    for (int t = 0; t < nkt; ++t) {
        unsigned char* rb = (t & 1) ? (LDS + 16384) : LDS;
        __syncthreads();  // drains tile-t staging (vmcnt 0) + rendezvous
        if (t + 1 < nkt) stage(t + 1, (t & 1) ? LDS : (LDS + 16384));

        // ---- QK^T (bf16x3): sacc[kt] = S[16q x 16kpos], kt = 0,1 ----
        f4v sacc[2];
#pragma unroll
        for (int kt = 0; kt < 2; kt++) sacc[kt] = (f4v){0.f, 0.f, 0.f, 0.f};
#pragma unroll
        for (int kt = 0; kt < 2; kt++) {
            const int krow = kt * 16 + l15;
            const int swz = (krow & 7) << 4;
#pragma unroll
            for (int c = 0; c < 2; c++) {
                const int kb = (krow * 128 + c * 64 + l4 * 16) ^ swz;
                s8v fkh = *(const s8v*)(rb + kb);
                s8v fkl = *(const s8v*)(rb + 4096 + kb);
                sacc[kt] = __builtin_amdgcn_mfma_f32_16x16x32_bf16(fql[c], fkh, sacc[kt], 0, 0, 0);
                sacc[kt] = __builtin_amdgcn_mfma_f32_16x16x32_bf16(fqh[c], fkl, sacc[kt], 0, 0, 0);
                sacc[kt] = __builtin_amdgcn_mfma_f32_16x16x32_bf16(fqh[c], fkh, sacc[kt], 0, 0, 0);
            }
        }

        // ---- online softmax per q-row; P -> LDS as bf16 hi/lo ----
        const int dk0 = t * 32 - p * 64;        // tile kpos offset vs stripe base
        const bool diag = (dk0 + 32 > 0);       // only final two tiles need masking
#pragma unroll
        for (int r = 0; r < 4; r++) {
            const int rowl = wq * 16 + l4 * 4 + r;  // local q row in stripe (0..63)
            float sv[2];
#pragma unroll
            for (int kt = 0; kt < 2; kt++) {
                sv[kt] = sacc[kt][r] * 0.125f;
                if (diag && (dk0 + kt * 16 + l15) > rowl) sv[kt] = -1e30f;
            }
            float pm = fmaxf(sv[0], sv[1]);
#pragma unroll
            for (int off = 1; off < 16; off <<= 1) pm = fmaxf(pm, __shfl_xor(pm, off, 64));
            const float mn = fmaxf(mrow[r], pm);
            const float cc = __expf(mrow[r] - mn);
            mrow[r] = mn;
            float ps[2];
#pragma unroll
            for (int kt = 0; kt < 2; kt++) ps[kt] = __expf(sv[kt] - mn);
            float psum = ps[0] + ps[1];
#pragma unroll
            for (int off = 1; off < 16; off <<= 1) psum += __shfl_xor(psum, off, 64);
            lrow[r] = lrow[r] * cc + psum;
#pragma unroll
            for (int ni = 0; ni < 4; ni++) oacc[ni][r] *= cc;
            const int rowP = l4 * 4 + r;
#pragma unroll
            for (int kt = 0; kt < 2; kt++) {
                const unsigned short ph = bf16_rne(ps[kt]);
                const unsigned short pl = bf16_rne(ps[kt] - bf16f(ph));
                const int pb = rowP * 64 + (kt * 16 + l15) * 2;
                *(unsigned short*)(Pw + pb) = ph;
                *(unsigned short*)(Pw + 1024 + pb) = pl;
            }
        }

        // ---- PV (bf16x3): O[16q x 64d] += P[16q x 32k] * VT[64d x 32k]^T ----
        s8v fph, fpl;
        {
            const int pb = l15 * 64 + l4 * 16;
            fph = *(const s8v*)(Pw + pb);
            fpl = *(const s8v*)(Pw + 1024 + pb);
        }
#pragma unroll
        for (int ni = 0; ni < 4; ni++) {
            const int vb = (ni * 16 + l15) * 64 + l4 * 16;
            s8v fvh = *(const s8v*)(rb + 8192 + vb);
            s8v fvl = *(const s8v*)(rb + 12288 + vb);
            oacc[ni] = __builtin_amdgcn_mfma_f32_16x16x32_bf16(fpl, fvh, oacc[ni], 0, 0, 0);
            oacc[ni] = __builtin_amdgcn_mfma_f32_16x16x32_bf16(fph, fvl, oacc[ni], 0, 0, 0);
            oacc[ni] = __builtin_amdgcn_mfma_f32_16x16x32_bf16(fph, fvh, oacc[ni], 0, 0, 0);
        }
    }

    // ---- epilogue: Ao [b][s][h*64+d] fp32 ----
#pragma unroll
    for (int r = 0; r < 4; r++) {
        const float inv = 1.0f / lrow[r];
        const int q = p * 64 + wq * 16 + l4 * 4 + r;
        float* orow = Ao + ((size_t)b * SEQ + q) * D_MODEL + h * DK;
#pragma unroll
        for (int ni = 0; ni < 4; ni++) orow[ni * 16 + l15] = oacc[ni][r] * inv;
    }
}

// ---------------------------------------------------------------------------
extern "C" void kernel_launch(void* const* d_in, const int* in_sizes, int n_in,
                              void* d_out, int out_size, void* d_ws, size_t ws_size,
                              hipStream_t stream) {
    const float* x  = (const float*)d_in[0];
    const float* Wq = (const float*)d_in[1];
    const float* bq = (const float*)d_in[2];
    const float* Wk = (const float*)d_in[3];
    const float* bk = (const float*)d_in[4];
    const float* Wv = (const float*)d_in[5];
    const float* bv = (const float*)d_in[6];
    const float* Wo = (const float*)d_in[7];
    const float* bo = (const float*)d_in[8];
    float* out = (float*)d_out;

    char* wsb = (char*)d_ws;  // footprint = 101,187,584 B (identical to benched round-2)
    unsigned short* xh  = (unsigned short*)(wsb);              // 8 MB (x hi; later Ao hi)
    unsigned short* xl  = (unsigned short*)(wsb + 8388608);    // 8 MB
    unsigned short* wt  = (unsigned short*)(wsb + 16777216);   // 16 MB: 8 x 2MB W splits
    unsigned short* Qh  = (unsigned short*)(wsb + 33554432);   // [bh][s][64] bf16, 8 MB each
    unsigned short* Ql  = (unsigned short*)(wsb + 41943040);
    unsigned short* Kh  = (unsigned short*)(wsb + 50331648);
    unsigned short* Kl  = (unsigned short*)(wsb + 58720256);
    unsigned short* Vh  = (unsigned short*)(wsb + 67108864);   // dead after vtrans
    unsigned short* Vl  = (unsigned short*)(wsb + 75497472);   // dead after vtrans
    unsigned short* VTh = (unsigned short*)(wsb + 83886080);   // [bh][64][s] bf16
    unsigned short* VTl = (unsigned short*)(wsb + 92274688);
    float* Ao = (float*)(wsb + 67108864);                      // 16 MB, overlays Vh/Vl
    float* ct = (float*)(wsb + 100663296);
    float* st = (float*)(wsb + 100925440);

    const size_t WSZ = 1048576;

    rope_tab<<<256, 256, 0, stream>>>(ct, st);
    splitk<<<1024, 256, 0, stream>>>(x, xh, xl, (MROWS * D_MODEL) / 4);
    wsplit<<<dim3(16, 16), 256, 0, stream>>>(Wq, wt + 0 * WSZ, wt + 1 * WSZ);
    wsplit<<<dim3(16, 16), 256, 0, stream>>>(Wk, wt + 2 * WSZ, wt + 3 * WSZ);
    wsplit<<<dim3(16, 16), 256, 0, stream>>>(Wv, wt + 4 * WSZ, wt + 5 * WSZ);
    wsplit<<<dim3(16, 16), 256, 0, stream>>>(Wo, wt + 6 * WSZ, wt + 7 * WSZ);

    gemm_b3<<<dim3(8, 32, 3), 256, 0, stream>>>(xh, xl,
        wt + 0 * WSZ, wt + 1 * WSZ, wt + 2 * WSZ, wt + 3 * WSZ, wt + 4 * WSZ, wt + 5 * WSZ,
        bq, bk, bv, nullptr, Qh, Ql, Kh, Kl, Vh, Vl, ct, st, 0);

    vtrans<<<dim3(SEQ / 64, 32), 256, 0, stream>>>(Vh, VTh);
    vtrans<<<dim3(SEQ / 64, 32), 256, 0, stream>>>(Vl, VTl);

    attn_mfma<<<dim3(1024), 256, 0, stream>>>(Qh, Ql, Kh, Kl, VTh, VTl, Ao);

    splitk<<<1024, 256, 0, stream>>>(Ao, xh, xl, (MROWS * D_MODEL) / 4);

    gemm_b3<<<dim3(8, 32, 1), 256, 0, stream>>>(xh, xl,
        wt + 6 * WSZ, wt + 7 * WSZ, wt + 6 * WSZ, wt + 7 * WSZ, wt + 6 * WSZ, wt + 7 * WSZ,
        bo, bo, bo, out, nullptr, nullptr, nullptr, nullptr, nullptr, nullptr, ct, st, 1);
}

// Round 8
// 296.025 us; speedup vs baseline: 5.7949x; 1.3071x over previous
//
#include <hip/hip_runtime.h>
#include <math.h>

#define D_MODEL 1024
#define NH 16
#define DK 64
#define SEQ 2048
#define BATCH 2
#define MROWS 4096

typedef __attribute__((ext_vector_type(8))) short s8v;   // 8 bf16 MFMA A/B frag
typedef __attribute__((ext_vector_type(4))) float f4v;   // MFMA C/D frag

// ---------------- helpers ----------------
__device__ __forceinline__ unsigned short bf16_rne(float x) {
    unsigned int u = __float_as_uint(x);
    unsigned int r = (u + 0x7FFFu + ((u >> 16) & 1u)) >> 16;
    return (unsigned short)r;
}
__device__ __forceinline__ float bf16f(unsigned short h) {
    return __uint_as_float(((unsigned int)h) << 16);
}
__device__ __forceinline__ void gll16(void* lds, const void* g) {
    // async global->LDS: LDS dest = wave-uniform base + lane*16; global src per-lane
    __builtin_amdgcn_global_load_lds((const __attribute__((address_space(1))) unsigned int*)g,
                                     (__attribute__((address_space(3))) unsigned int*)lds,
                                     16, 0, 0);
}

// ---------------- RoPE tables ----------------
__global__ __launch_bounds__(256) void rope_tab(float* __restrict__ ct, float* __restrict__ st) {
    int i = blockIdx.x * 256 + threadIdx.x;  // 0 .. SEQ*32-1
    int s = i >> 5, p = i & 31;
    double inv = exp(-((double)(2 * p) / 64.0) * 9.210340371976184);
    double f = (double)s * inv;
    ct[i] = (float)cos(f);
    st[i] = (float)sin(f);
}

// ---------------- fp32 -> bf16 (hi only) cast ----------------
__global__ __launch_bounds__(256) void casth(const float* __restrict__ src,
                                             unsigned short* __restrict__ hi, int n4) {
    int i = blockIdx.x * 256 + threadIdx.x;
    const int stride = gridDim.x * 256;
    for (; i < n4; i += stride) {
        const float4 v = ((const float4*)src)[i];
        ushort4 h;
        h.x = bf16_rne(v.x);
        h.y = bf16_rne(v.y);
        h.z = bf16_rne(v.z);
        h.w = bf16_rne(v.w);
        ((ushort4*)hi)[i] = h;
    }
}

// ---------------- W[k][n] -> WT[n][k] split-transpose ----------------
__global__ __launch_bounds__(256) void wsplit(const float* __restrict__ W,
                                              unsigned short* __restrict__ Th,
                                              unsigned short* __restrict__ Tl) {
    __shared__ float t[64][65];
    const int k0 = blockIdx.y * 64, n0 = blockIdx.x * 64;
    const int tid = threadIdx.x;
#pragma unroll
    for (int i = 0; i < 4; i++) {
        int u = tid + i * 256;
        int r = u >> 4, c = (u & 15) * 4;
        float4 v = *(const float4*)(W + (size_t)(k0 + r) * D_MODEL + n0 + c);
        t[r][c] = v.x; t[r][c + 1] = v.y; t[r][c + 2] = v.z; t[r][c + 3] = v.w;
    }
    __syncthreads();
#pragma unroll
    for (int i = 0; i < 4; i++) {
        int u = tid + i * 256;
        int nr = u >> 4, kc = (u & 15) * 4;
        ushort4 h, l;
        float x0 = t[kc + 0][nr], x1 = t[kc + 1][nr], x2 = t[kc + 2][nr], x3 = t[kc + 3][nr];
        h.x = bf16_rne(x0); l.x = bf16_rne(x0 - bf16f(h.x));
        h.y = bf16_rne(x1); l.y = bf16_rne(x1 - bf16f(h.y));
        h.z = bf16_rne(x2); l.z = bf16_rne(x2 - bf16f(h.z));
        h.w = bf16_rne(x3); l.w = bf16_rne(x3 - bf16f(h.w));
        *(ushort4*)(Th + (size_t)(n0 + nr) * D_MODEL + k0 + kc) = h;
        *(ushort4*)(Tl + (size_t)(n0 + nr) * D_MODEL + k0 + kc) = l;
    }
}

// ---------------- Vx [bh][s][64] bf16 -> VTx [bh][64][s] bf16 ----------------
__global__ __launch_bounds__(256) void vtrans(const unsigned short* __restrict__ Vh,
                                              unsigned short* __restrict__ VT) {
    __shared__ unsigned short t[64][65];
    const int bh = blockIdx.y, s0 = blockIdx.x * 64;
    const int tid = threadIdx.x;
    const int r = tid >> 2, c16 = (tid & 3) * 16;
#pragma unroll
    for (int i = 0; i < 2; i++) {
        s8v v = *(const s8v*)(Vh + ((size_t)bh * SEQ + s0 + r) * 64 + c16 + i * 8);
#pragma unroll
        for (int j = 0; j < 8; j++) t[r][c16 + i * 8 + j] = ((unsigned short*)&v)[j];
    }
    __syncthreads();
    const int d = tid >> 2, sc = (tid & 3) * 16;
#pragma unroll
    for (int i = 0; i < 2; i++) {
        s8v o;
#pragma unroll
        for (int j = 0; j < 8; j++) ((unsigned short*)&o)[j] = t[sc + i * 8 + j][d];
        *(s8v*)(VT + ((size_t)bh * 64 + d) * SEQ + s0 + sc + i * 8) = o;
    }
}

// ---------------- bf16x2 MFMA GEMM: C = Ah @ (Bh+Bl)^T + bias ----------------
// mode 0: z selects Q/K/V; RoPE fused for z<2; writes bf16 hi/lo pairs, [bh][s][d]
// mode 1: plain fp32 write out[m][n]
__global__ __launch_bounds__(256, 2) void gemm_b3(
    const unsigned short* __restrict__ Ah,
    const unsigned short* B0h, const unsigned short* B0l,
    const unsigned short* B1h, const unsigned short* B1l,
    const unsigned short* B2h, const unsigned short* B2l,
    const float* b0, const float* b1, const float* b2,
    float* out1,
    unsigned short* qh, unsigned short* ql, unsigned short* kh2, unsigned short* kl2,
    unsigned short* vh, unsigned short* vl,
    const float* __restrict__ ct, const float* __restrict__ st, int mode) {

    const int z = blockIdx.z;
    const unsigned short* Bh = (z == 0) ? B0h : ((z == 1) ? B1h : B2h);
    const unsigned short* Bl = (z == 0) ? B0l : ((z == 1) ? B1l : B2l);
    const float* bias = (z == 0) ? b0 : ((z == 1) ? b1 : b2);

    const int m0 = blockIdx.y * 128, n0 = blockIdx.x * 128;
    const int tid = threadIdx.x, w = tid >> 6, L = tid & 63;
    const int wr = w >> 1, wc = w & 1;

    __shared__ unsigned short sm[3][128][32];  // [Ah|Bh|Bl]

    f4v acc[4][4];
#pragma unroll
    for (int i = 0; i < 4; i++)
#pragma unroll
        for (int j = 0; j < 4; j++) acc[i][j] = (f4v){0.f, 0.f, 0.f, 0.f};

    const int fr = L & 15, kh = (L >> 4) * 8;

    for (int k0 = 0; k0 < D_MODEL; k0 += 32) {
#pragma unroll
        for (int t = 0; t < 2; t++) {
            const int i = w * 2 + t;
            const int row = i * 16 + (L >> 2);
            const size_t kof = (size_t)k0 + (L & 3) * 8;
            gll16(&sm[0][i * 16][0], Ah + (size_t)(m0 + row) * D_MODEL + kof);
            gll16(&sm[1][i * 16][0], Bh + (size_t)(n0 + row) * D_MODEL + kof);
            gll16(&sm[2][i * 16][0], Bl + (size_t)(n0 + row) * D_MODEL + kof);
        }
        __syncthreads();

        s8v fah[4], fbh[4], fbl[4];
#pragma unroll
        for (int mi = 0; mi < 4; mi++)
            fah[mi] = *(const s8v*)&sm[0][wr * 64 + mi * 16 + fr][kh];
#pragma unroll
        for (int ni = 0; ni < 4; ni++) {
            fbh[ni] = *(const s8v*)&sm[1][wc * 64 + ni * 16 + fr][kh];
            fbl[ni] = *(const s8v*)&sm[2][wc * 64 + ni * 16 + fr][kh];
        }
#pragma unroll
        for (int mi = 0; mi < 4; mi++)
#pragma unroll
            for (int ni = 0; ni < 4; ni++) {
                acc[mi][ni] = __builtin_amdgcn_mfma_f32_16x16x32_bf16(fah[mi], fbl[ni], acc[mi][ni], 0, 0, 0);
                acc[mi][ni] = __builtin_amdgcn_mfma_f32_16x16x32_bf16(fah[mi], fbh[ni], acc[mi][ni], 0, 0, 0);
            }
        __syncthreads();
    }

    // epilogue: C/D map (session-verified on HW): col = lane&15, row = (lane>>4)*4 + reg
#pragma unroll
    for (int mi = 0; mi < 4; mi++)
#pragma unroll
        for (int ni = 0; ni < 4; ni++) {
            const int col = n0 + wc * 64 + ni * 16 + fr;
            const float bv = bias[col];
#pragma unroll
            for (int r = 0; r < 4; r++) {
                const int row = m0 + wr * 64 + mi * 16 + (L >> 4) * 4 + r;
                float v = acc[mi][ni][r] + bv;
                if (mode == 1) {
                    out1[(size_t)row * D_MODEL + col] = v;
                } else {
                    const int b = row >> 11, s = row & (SEQ - 1);
                    const int h = col >> 6, d = col & 63;
                    float res;
                    if (z < 2) {  // RoPE: even/odd adjacent cols are in adjacent lanes
                        const float pr = __shfl_xor(v, 1, 64);
                        const int pp = d >> 1;
                        const float cv = ct[s * 32 + pp], sv = st[s * 32 + pp];
                        res = (L & 1) ? fmaf(pr, sv, v * cv) : fmaf(v, cv, -(pr * sv));
                    } else {
                        res = v;
                    }
                    const size_t idx = ((size_t)(b * NH + h) * SEQ + s) * DK + d;
                    const unsigned short rh = bf16_rne(res);
                    const unsigned short rl = bf16_rne(res - bf16f(rh));
                    if (z == 0)      { qh[idx] = rh;  ql[idx] = rl; }
                    else if (z == 1) { kh2[idx] = rh; kl2[idx] = rl; }
                    else             { vh[idx] = rh;  vl[idx] = rl; }
                }
            }
        }
}

// ---------------- MFMA flash attention v2: swapped QK^T, in-register P ----------------
// Block = 4 waves = one 64-query stripe p of one (b,h). 32-kpos tiles, double-buffered,
// __syncthreads()-drained staging (proven sync). S^T = K·Q^T via mfma(K,Q): lane owns
// 8 scores of ONE q-row -> softmax is lane-local + 4 shuffles. P^T built in-register
// (bf16 pack + 2-round xor butterfly), PV: O^T = (Vh+Vl)·P^T. No P LDS. V^T LDS
// swizzled (c ^= ((row>>1)&3)<<4) via pre-swizzled global source.
__global__ __launch_bounds__(256, 2) void attn_mfma(
    const unsigned short* __restrict__ Qh, const unsigned short* __restrict__ Ql,
    const unsigned short* __restrict__ Kh, const unsigned short* __restrict__ Kl,
    const unsigned short* __restrict__ VTh, const unsigned short* __restrict__ VTl,
    unsigned short* __restrict__ Aoh) {

    // LDS: 2 bufs x {Kh 4K | Kl 4K | VTh 4K | VTl 4K}
    __shared__ __align__(16) unsigned char LDS[32768];
    const int bx = blockIdx.x;
    const int bh = bx & 31;
    const int p = 31 - (bx >> 5);       // big stripes first
    const int tid = threadIdx.x;
    const int wq = tid >> 6, lane = tid & 63;
    const int b = bh >> 4, h = bh & 15;
    const int l15 = lane & 15, l4 = lane >> 4;

    // Q fragments (B-operand): lane l15 = q-col, k(d) = c*32 + l4*8 + j
    const int qbase = p * 64 + wq * 16;
    s8v fqh[2], fql[2];
    {
        const size_t rowB = ((size_t)bh * SEQ + qbase + l15) * 128;  // 128B per row
        const int kof = l4 * 16;
        fqh[0] = *(const s8v*)((const char*)Qh + rowB + kof);
        fqh[1] = *(const s8v*)((const char*)Qh + rowB + kof + 64);
        fql[0] = *(const s8v*)((const char*)Ql + rowB + kof);
        fql[1] = *(const s8v*)((const char*)Ql + rowB + kof + 64);
    }

    f4v oacc[4];  // O^T: [d = ni*16 + l4*4 + r][q = l15]
#pragma unroll
    for (int i = 0; i < 4; i++) oacc[i] = (f4v){0.f, 0.f, 0.f, 0.f};
    float m = -1e30f, l = 0.f;  // per-lane (q = l15); consistent across l4 copies

    const int nkt = 2 * (p + 1);  // 32-kpos tiles incl. diagonal

    // stage one 32-kpos tile into buffer bb (16KB): each wave covers 1KB/array
    auto stage = [&](int t, unsigned char* bb) {
        {   // K hi/lo: rows of 128B, XOR-swizzled via pre-swizzled source
            const int row = wq * 8 + (lane >> 3);
            const int off = (lane & 7) * 16;
            const int soff = off ^ ((row & 7) << 4);
            const size_t kB = ((size_t)bh * SEQ + (size_t)t * 32 + row) * 128 + soff;
            gll16(bb + 0    + wq * 1024, (const char*)Kh + kB);
            gll16(bb + 4096 + wq * 1024, (const char*)Kl + kB);
        }
        {   // V^T hi/lo: rows of 64B (d-major, 32 kpos), swizzled source
            const int row = wq * 16 + (lane >> 2);
            const int off = (lane & 3) * 16;
            const int soff = off ^ (((row >> 1) & 3) << 4);
            const size_t vB = (((size_t)bh * 64 + row) * SEQ + (size_t)t * 32) * 2 + soff;
            gll16(bb + 8192  + wq * 1024, (const char*)VTh + vB);
            gll16(bb + 12288 + wq * 1024, (const char*)VTl + vB);
        }
    };

    stage(0, LDS);

    for (int t = 0; t < nkt; ++t) {
        unsigned char* rb = (t & 1) ? (LDS + 16384) : LDS;
        __syncthreads();  // drains tile-t staging (vmcnt 0) + rendezvous
        if (t + 1 < nkt) stage(t + 1, (t & 1) ? LDS : (LDS + 16384));

        // ---- QK^T swapped (bf16x3): sacc[kt] = S^T[kpos = kt*16 + l4*4 + r][q = l15] ----
        f4v sacc[2];
#pragma unroll
        for (int kt = 0; kt < 2; kt++) sacc[kt] = (f4v){0.f, 0.f, 0.f, 0.f};
#pragma unroll
        for (int kt = 0; kt < 2; kt++) {
            const int krow = kt * 16 + l15;
            const int swz = (krow & 7) << 4;
#pragma unroll
            for (int c = 0; c < 2; c++) {
                const int kb = (krow * 128 + c * 64 + l4 * 16) ^ swz;
                s8v fkh = *(const s8v*)(rb + kb);
                s8v fkl = *(const s8v*)(rb + 4096 + kb);
                sacc[kt] = __builtin_amdgcn_mfma_f32_16x16x32_bf16(fkh, fql[c], sacc[kt], 0, 0, 0);
                sacc[kt] = __builtin_amdgcn_mfma_f32_16x16x32_bf16(fkl, fqh[c], sacc[kt], 0, 0, 0);
                sacc[kt] = __builtin_amdgcn_mfma_f32_16x16x32_bf16(fkh, fqh[c], sacc[kt], 0, 0, 0);
            }
        }

        // ---- lane-local online softmax (q = l15) ----
        const int dk0 = t * 32 - p * 64;        // tile kpos offset vs stripe base
        const int qlocal = wq * 16 + l15;
        float sv[8];
#pragma unroll
        for (int kt = 0; kt < 2; kt++)
#pragma unroll
            for (int r = 0; r < 4; r++) {
                const int kp = dk0 + kt * 16 + l4 * 4 + r;
                float s = sacc[kt][r] * 0.125f;
                sv[kt * 4 + r] = (kp > qlocal) ? -1e30f : s;
            }
        float pm = fmaxf(fmaxf(fmaxf(sv[0], sv[1]), fmaxf(sv[2], sv[3])),
                         fmaxf(fmaxf(sv[4], sv[5]), fmaxf(sv[6], sv[7])));
        pm = fmaxf(pm, __shfl_xor(pm, 16, 64));
        pm = fmaxf(pm, __shfl_xor(pm, 32, 64));
        const float mn = fmaxf(m, pm);
        const float cc = __expf(m - mn);
        m = mn;
        float ps[8], psum = 0.f;
#pragma unroll
        for (int i = 0; i < 8; i++) { ps[i] = __expf(sv[i] - mn); psum += ps[i]; }
        psum += __shfl_xor(psum, 16, 64);
        psum += __shfl_xor(psum, 32, 64);
        l = l * cc + psum;
#pragma unroll
        for (int ni = 0; ni < 4; ni++)
#pragma unroll
            for (int r = 0; r < 4; r++) oacc[ni][r] *= cc;

        // ---- build P^T B-frag in-register: lane needs P[kpos = l4*8 + j][q = l15] ----
        // local pairs (kpos/2): {2l4, 2l4+1, 2l4+8, 2l4+9} -> target {4l4..4l4+3}
        unsigned w0 = (unsigned)bf16_rne(ps[0]) | ((unsigned)bf16_rne(ps[1]) << 16);
        unsigned w1 = (unsigned)bf16_rne(ps[2]) | ((unsigned)bf16_rne(ps[3]) << 16);
        unsigned w2 = (unsigned)bf16_rne(ps[4]) | ((unsigned)bf16_rne(ps[5]) << 16);
        unsigned w3 = (unsigned)bf16_rne(ps[6]) | ((unsigned)bf16_rne(ps[7]) << 16);
        const bool lo2 = (l4 < 2);
        unsigned sA = lo2 ? w2 : w0, sB = lo2 ? w3 : w1;
        unsigned rA = (unsigned)__shfl_xor((int)sA, 32, 64);
        unsigned rB = (unsigned)__shfl_xor((int)sB, 32, 64);
        unsigned q0 = lo2 ? w0 : rA, q1 = lo2 ? w1 : rB;
        unsigned q2 = lo2 ? rA : w2, q3 = lo2 ? rB : w3;
        const bool ev = ((l4 & 1) == 0);
        unsigned sC = ev ? q2 : q0, sD = ev ? q3 : q1;
        unsigned rC = (unsigned)__shfl_xor((int)sC, 16, 64);
        unsigned rD = (unsigned)__shfl_xor((int)sD, 16, 64);
        unsigned d0 = ev ? q0 : rC, d1 = ev ? q1 : rD;
        unsigned d2 = ev ? rC : q2, d3 = ev ? rD : q3;
        s8v fp;
        ((unsigned*)&fp)[0] = d0; ((unsigned*)&fp)[1] = d1;
        ((unsigned*)&fp)[2] = d2; ((unsigned*)&fp)[3] = d3;

        // ---- PV: O^T[d][q] += V^T[d][kpos] * P^T[kpos][q]  (V hi+lo, P bf16) ----
#pragma unroll
        for (int ni = 0; ni < 4; ni++) {
            const int row = ni * 16 + l15;
            const int vb = row * 64 + ((l4 * 16) ^ (((row >> 1) & 3) << 4));
            s8v fvh = *(const s8v*)(rb + 8192 + vb);
            s8v fvl = *(const s8v*)(rb + 12288 + vb);
            oacc[ni] = __builtin_amdgcn_mfma_f32_16x16x32_bf16(fvl, fp, oacc[ni], 0, 0, 0);
            oacc[ni] = __builtin_amdgcn_mfma_f32_16x16x32_bf16(fvh, fp, oacc[ni], 0, 0, 0);
        }
    }

    // ---- epilogue: Aoh bf16 [b][s][h*64 + d], d = ni*16 + l4*4 + r ----
    const float inv = 1.0f / l;
    const int q = p * 64 + wq * 16 + l15;
    unsigned short* obase = Aoh + ((size_t)b * SEQ + q) * D_MODEL + h * DK;
#pragma unroll
    for (int ni = 0; ni < 4; ni++) {
        ushort4 o;
        o.x = bf16_rne(oacc[ni][0] * inv);
        o.y = bf16_rne(oacc[ni][1] * inv);
        o.z = bf16_rne(oacc[ni][2] * inv);
        o.w = bf16_rne(oacc[ni][3] * inv);
        *(ushort4*)(obase + ni * 16 + l4 * 4) = o;
    }
}

// ---------------------------------------------------------------------------
extern "C" void kernel_launch(void* const* d_in, const int* in_sizes, int n_in,
                              void* d_out, int out_size, void* d_ws, size_t ws_size,
                              hipStream_t stream) {
    const float* x  = (const float*)d_in[0];
    const float* Wq = (const float*)d_in[1];
    const float* bq = (const float*)d_in[2];
    const float* Wk = (const float*)d_in[3];
    const float* bk = (const float*)d_in[4];
    const float* Wv = (const float*)d_in[5];
    const float* bv = (const float*)d_in[6];
    const float* Wo = (const float*)d_in[7];
    const float* bo = (const float*)d_in[8];
    float* out = (float*)d_out;

    char* wsb = (char*)d_ws;  // footprint = 101,187,584 B (same as benched round-2)
    unsigned short* xh  = (unsigned short*)(wsb);              // 8 MB: x cast bf16
    unsigned short* Aoh = (unsigned short*)(wsb + 8388608);    // 8 MB: attn out bf16
    unsigned short* wt  = (unsigned short*)(wsb + 16777216);   // 16 MB: 8 x 2MB W splits
    unsigned short* Qh  = (unsigned short*)(wsb + 33554432);   // [bh][s][64] bf16, 8 MB each
    unsigned short* Ql  = (unsigned short*)(wsb + 41943040);
    unsigned short* Kh  = (unsigned short*)(wsb + 50331648);
    unsigned short* Kl  = (unsigned short*)(wsb + 58720256);
    unsigned short* Vh  = (unsigned short*)(wsb + 67108864);
    unsigned short* Vl  = (unsigned short*)(wsb + 75497472);
    unsigned short* VTh = (unsigned short*)(wsb + 83886080);   // [bh][64][s] bf16
    unsigned short* VTl = (unsigned short*)(wsb + 92274688);
    float* ct = (float*)(wsb + 100663296);
    float* st = (float*)(wsb + 100925440);

    const size_t WSZ = 1048576;

    rope_tab<<<256, 256, 0, stream>>>(ct, st);
    casth<<<1024, 256, 0, stream>>>(x, xh, (MROWS * D_MODEL) / 4);
    wsplit<<<dim3(16, 16), 256, 0, stream>>>(Wq, wt + 0 * WSZ, wt + 1 * WSZ);
    wsplit<<<dim3(16, 16), 256, 0, stream>>>(Wk, wt + 2 * WSZ, wt + 3 * WSZ);
    wsplit<<<dim3(16, 16), 256, 0, stream>>>(Wv, wt + 4 * WSZ, wt + 5 * WSZ);
    wsplit<<<dim3(16, 16), 256, 0, stream>>>(Wo, wt + 6 * WSZ, wt + 7 * WSZ);

    gemm_b3<<<dim3(8, 32, 3), 256, 0, stream>>>(xh,
        wt + 0 * WSZ, wt + 1 * WSZ, wt + 2 * WSZ, wt + 3 * WSZ, wt + 4 * WSZ, wt + 5 * WSZ,
        bq, bk, bv, nullptr, Qh, Ql, Kh, Kl, Vh, Vl, ct, st, 0);

    vtrans<<<dim3(SEQ / 64, 32), 256, 0, stream>>>(Vh, VTh);
    vtrans<<<dim3(SEQ / 64, 32), 256, 0, stream>>>(Vl, VTl);

    attn_mfma<<<dim3(1024), 256, 0, stream>>>(Qh, Ql, Kh, Kl, VTh, VTl, Aoh);

    gemm_b3<<<dim3(8, 32, 1), 256, 0, stream>>>(Aoh,
        wt + 6 * WSZ, wt + 7 * WSZ, wt + 6 * WSZ, wt + 7 * WSZ, wt + 6 * WSZ, wt + 7 * WSZ,
        bo, bo, bo, out, nullptr, nullptr, nullptr, nullptr, nullptr, nullptr, ct, st, 1);
}

// Round 9
// 295.408 us; speedup vs baseline: 5.8070x; 1.0021x over previous
//
#include <hip/hip_runtime.h>
#include <math.h>

#define D_MODEL 1024
#define NH 16
#define DK 64
#define SEQ 2048
#define BATCH 2
#define MROWS 4096

typedef __attribute__((ext_vector_type(8))) short s8v;   // 8 bf16 MFMA A/B frag
typedef __attribute__((ext_vector_type(4))) float f4v;   // MFMA C/D frag

// ---------------- helpers ----------------
__device__ __forceinline__ unsigned short bf16_rne(float x) {
    unsigned int u = __float_as_uint(x);
    unsigned int r = (u + 0x7FFFu + ((u >> 16) & 1u)) >> 16;
    return (unsigned short)r;
}
__device__ __forceinline__ float bf16f(unsigned short h) {
    return __uint_as_float(((unsigned int)h) << 16);
}
__device__ __forceinline__ void gll16(void* lds, const void* g) {
    // async global->LDS: LDS dest = wave-uniform base + lane*16; global src per-lane
    __builtin_amdgcn_global_load_lds((const __attribute__((address_space(1))) unsigned int*)g,
                                     (__attribute__((address_space(3))) unsigned int*)lds,
                                     16, 0, 0);
}

// ---------------- RoPE tables ----------------
__global__ __launch_bounds__(256) void rope_tab(float* __restrict__ ct, float* __restrict__ st) {
    int i = blockIdx.x * 256 + threadIdx.x;  // 0 .. SEQ*32-1
    int s = i >> 5, p = i & 31;
    double inv = exp(-((double)(2 * p) / 64.0) * 9.210340371976184);
    double f = (double)s * inv;
    ct[i] = (float)cos(f);
    st[i] = (float)sin(f);
}

// ---------------- fp32 -> bf16 (hi only) cast ----------------
__global__ __launch_bounds__(256) void casth(const float* __restrict__ src,
                                             unsigned short* __restrict__ hi, int n4) {
    int i = blockIdx.x * 256 + threadIdx.x;
    const int stride = gridDim.x * 256;
    for (; i < n4; i += stride) {
        const float4 v = ((const float4*)src)[i];
        ushort4 h;
        h.x = bf16_rne(v.x);
        h.y = bf16_rne(v.y);
        h.z = bf16_rne(v.z);
        h.w = bf16_rne(v.w);
        ((ushort4*)hi)[i] = h;
    }
}

// ---------------- W[k][n] -> WT[n][k] transpose, bf16 hi only ----------------
__global__ __launch_bounds__(256) void wtrans(const float* __restrict__ W,
                                              unsigned short* __restrict__ Th) {
    __shared__ float t[64][65];
    const int k0 = blockIdx.y * 64, n0 = blockIdx.x * 64;
    const int tid = threadIdx.x;
#pragma unroll
    for (int i = 0; i < 4; i++) {
        int u = tid + i * 256;
        int r = u >> 4, c = (u & 15) * 4;
        float4 v = *(const float4*)(W + (size_t)(k0 + r) * D_MODEL + n0 + c);
        t[r][c] = v.x; t[r][c + 1] = v.y; t[r][c + 2] = v.z; t[r][c + 3] = v.w;
    }
    __syncthreads();
#pragma unroll
    for (int i = 0; i < 4; i++) {
        int u = tid + i * 256;
        int nr = u >> 4, kc = (u & 15) * 4;
        ushort4 h;
        h.x = bf16_rne(t[kc + 0][nr]);
        h.y = bf16_rne(t[kc + 1][nr]);
        h.z = bf16_rne(t[kc + 2][nr]);
        h.w = bf16_rne(t[kc + 3][nr]);
        *(ushort4*)(Th + (size_t)(n0 + nr) * D_MODEL + k0 + kc) = h;
    }
}

// ---------------- W[k][n] -> WT[n][k] split-transpose (hi+lo, for Wo) ----------------
__global__ __launch_bounds__(256) void wsplit(const float* __restrict__ W,
                                              unsigned short* __restrict__ Th,
                                              unsigned short* __restrict__ Tl) {
    __shared__ float t[64][65];
    const int k0 = blockIdx.y * 64, n0 = blockIdx.x * 64;
    const int tid = threadIdx.x;
#pragma unroll
    for (int i = 0; i < 4; i++) {
        int u = tid + i * 256;
        int r = u >> 4, c = (u & 15) * 4;
        float4 v = *(const float4*)(W + (size_t)(k0 + r) * D_MODEL + n0 + c);
        t[r][c] = v.x; t[r][c + 1] = v.y; t[r][c + 2] = v.z; t[r][c + 3] = v.w;
    }
    __syncthreads();
#pragma unroll
    for (int i = 0; i < 4; i++) {
        int u = tid + i * 256;
        int nr = u >> 4, kc = (u & 15) * 4;
        ushort4 h, l;
        float x0 = t[kc + 0][nr], x1 = t[kc + 1][nr], x2 = t[kc + 2][nr], x3 = t[kc + 3][nr];
        h.x = bf16_rne(x0); l.x = bf16_rne(x0 - bf16f(h.x));
        h.y = bf16_rne(x1); l.y = bf16_rne(x1 - bf16f(h.y));
        h.z = bf16_rne(x2); l.z = bf16_rne(x2 - bf16f(h.z));
        h.w = bf16_rne(x3); l.w = bf16_rne(x3 - bf16f(h.w));
        *(ushort4*)(Th + (size_t)(n0 + nr) * D_MODEL + k0 + kc) = h;
        *(ushort4*)(Tl + (size_t)(n0 + nr) * D_MODEL + k0 + kc) = l;
    }
}

// ---------------- Vx [bh][s][64] bf16 -> VTx [bh][64][s] bf16 ----------------
__global__ __launch_bounds__(256) void vtrans(const unsigned short* __restrict__ Vh,
                                              unsigned short* __restrict__ VT) {
    __shared__ unsigned short t[64][65];
    const int bh = blockIdx.y, s0 = blockIdx.x * 64;
    const int tid = threadIdx.x;
    const int r = tid >> 2, c16 = (tid & 3) * 16;
#pragma unroll
    for (int i = 0; i < 2; i++) {
        s8v v = *(const s8v*)(Vh + ((size_t)bh * SEQ + s0 + r) * 64 + c16 + i * 8);
#pragma unroll
        for (int j = 0; j < 8; j++) t[r][c16 + i * 8 + j] = ((unsigned short*)&v)[j];
    }
    __syncthreads();
    const int d = tid >> 2, sc = (tid & 3) * 16;
#pragma unroll
    for (int i = 0; i < 2; i++) {
        s8v o;
#pragma unroll
        for (int j = 0; j < 8; j++) ((unsigned short*)&o)[j] = t[sc + i * 8 + j][d];
        *(s8v*)(VT + ((size_t)bh * 64 + d) * SEQ + s0 + sc + i * 8) = o;
    }
}

// ---------------- QKV GEMM (pure bf16): [Q|K|V] = x @ W^T + b, RoPE fused ----------------
// Frag-linear LDS: lane L's 16B gll16 block IS the MFMA frag block (row=L&15, kchunk=L>>4)
// -> all LDS reads are base + lane*16 (conflict-free). z selects Q/K/V; writes hi/lo pairs.
__global__ __launch_bounds__(256, 2) void gemm_qkv(
    const unsigned short* __restrict__ Ah,
    const unsigned short* __restrict__ B0h, const unsigned short* __restrict__ B1h,
    const unsigned short* __restrict__ B2h,
    const float* b0, const float* b1, const float* b2,
    unsigned short* qh, unsigned short* ql, unsigned short* kh2, unsigned short* kl2,
    unsigned short* vh, unsigned short* vl,
    const float* __restrict__ ct, const float* __restrict__ st) {

    const int z = blockIdx.z;
    const unsigned short* Bh = (z == 0) ? B0h : ((z == 1) ? B1h : B2h);
    const float* bias = (z == 0) ? b0 : ((z == 1) ? b1 : b2);

    const int m0 = blockIdx.y * 128, n0 = blockIdx.x * 128;
    const int tid = threadIdx.x, w = tid >> 6, L = tid & 63;
    const int wr = w >> 1, wc = w & 1;
    const int l15 = L & 15, l4 = L >> 4;

    __shared__ __align__(16) unsigned char sm[16384];  // A 8KB | B 8KB

    f4v acc[4][4];
#pragma unroll
    for (int i = 0; i < 4; i++)
#pragma unroll
        for (int j = 0; j < 4; j++) acc[i][j] = (f4v){0.f, 0.f, 0.f, 0.f};

    for (int k0 = 0; k0 < D_MODEL; k0 += 32) {
#pragma unroll
        for (int t = 0; t < 4; t++) {
            const int i = w * 4 + t;  // chunk 0..15: 0-7 = A rows, 8-15 = B rows
            const size_t row = (i < 8) ? (size_t)(m0 + i * 16 + l15)
                                       : (size_t)(n0 + (i - 8) * 16 + l15);
            const unsigned short* src = (i < 8) ? Ah : Bh;
            gll16(sm + i * 1024, src + row * D_MODEL + k0 + l4 * 8);
        }
        __syncthreads();

        s8v fa[4], fb[4];
#pragma unroll
        for (int mi = 0; mi < 4; mi++)
            fa[mi] = *(const s8v*)(sm + ((wr * 4 + mi) << 10) + L * 16);
#pragma unroll
        for (int ni = 0; ni < 4; ni++)
            fb[ni] = *(const s8v*)(sm + 8192 + ((wc * 4 + ni) << 10) + L * 16);
#pragma unroll
        for (int mi = 0; mi < 4; mi++)
#pragma unroll
            for (int ni = 0; ni < 4; ni++)
                acc[mi][ni] = __builtin_amdgcn_mfma_f32_16x16x32_bf16(fa[mi], fb[ni], acc[mi][ni], 0, 0, 0);
        __syncthreads();
    }

    // epilogue: C/D map (HW-verified): col = lane&15, row = (lane>>4)*4 + reg
#pragma unroll
    for (int mi = 0; mi < 4; mi++)
#pragma unroll
        for (int ni = 0; ni < 4; ni++) {
            const int col = n0 + wc * 64 + ni * 16 + l15;
            const float bv = bias[col];
#pragma unroll
            for (int r = 0; r < 4; r++) {
                const int row = m0 + wr * 64 + mi * 16 + l4 * 4 + r;
                const float v = acc[mi][ni][r] + bv;
                const int b = row >> 11, s = row & (SEQ - 1);
                const int h = col >> 6, d = col & 63;
                float res;
                if (z < 2) {  // RoPE: even/odd adjacent cols are in adjacent lanes
                    const float pr = __shfl_xor(v, 1, 64);
                    const int pp = d >> 1;
                    const float cv = ct[s * 32 + pp], sv = st[s * 32 + pp];
                    res = (L & 1) ? fmaf(pr, sv, v * cv) : fmaf(v, cv, -(pr * sv));
                } else {
                    res = v;
                }
                const size_t idx = ((size_t)(b * NH + h) * SEQ + s) * DK + d;
                const unsigned short rh = bf16_rne(res);
                const unsigned short rl = bf16_rne(res - bf16f(rh));
                if (z == 0)      { qh[idx] = rh;  ql[idx] = rl; }
                else if (z == 1) { kh2[idx] = rh; kl2[idx] = rl; }
                else             { vh[idx] = rh;  vl[idx] = rl; }
            }
        }
}

// ---------------- out GEMM (bf16x2: A @ (Bh+Bl)^T + bias), 64x128 tile ----------------
__global__ __launch_bounds__(256, 2) void gemm_out(
    const unsigned short* __restrict__ Ah,
    const unsigned short* __restrict__ Bh, const unsigned short* __restrict__ Bl,
    const float* __restrict__ bias, float* __restrict__ out1) {

    const int m0 = blockIdx.y * 64, n0 = blockIdx.x * 128;
    const int tid = threadIdx.x, w = tid >> 6, L = tid & 63;
    const int wr = w >> 1, wc = w & 1;
    const int l15 = L & 15, l4 = L >> 4;

    __shared__ __align__(16) unsigned char sm[20480];  // A 4KB | Bh 8KB | Bl 8KB

    f4v acc[2][4];
#pragma unroll
    for (int i = 0; i < 2; i++)
#pragma unroll
        for (int j = 0; j < 4; j++) acc[i][j] = (f4v){0.f, 0.f, 0.f, 0.f};

    for (int k0 = 0; k0 < D_MODEL; k0 += 32) {
#pragma unroll
        for (int t = 0; t < 5; t++) {
            const int i = w * 5 + t;  // chunk 0..19: 0-3 A, 4-11 Bh, 12-19 Bl
            const unsigned short* src;
            size_t row;
            if (i < 4)        { src = Ah; row = (size_t)(m0 + i * 16 + l15); }
            else if (i < 12)  { src = Bh; row = (size_t)(n0 + (i - 4) * 16 + l15); }
            else              { src = Bl; row = (size_t)(n0 + (i - 12) * 16 + l15); }
            gll16(sm + i * 1024, src + row * D_MODEL + k0 + l4 * 8);
        }
        __syncthreads();

        s8v fa[2], fbh[4], fbl[4];
#pragma unroll
        for (int mi = 0; mi < 2; mi++)
            fa[mi] = *(const s8v*)(sm + ((wr * 2 + mi) << 10) + L * 16);
#pragma unroll
        for (int ni = 0; ni < 4; ni++) {
            fbh[ni] = *(const s8v*)(sm + 4096 + ((wc * 4 + ni) << 10) + L * 16);
            fbl[ni] = *(const s8v*)(sm + 12288 + ((wc * 4 + ni) << 10) + L * 16);
        }
#pragma unroll
        for (int mi = 0; mi < 2; mi++)
#pragma unroll
            for (int ni = 0; ni < 4; ni++) {
                acc[mi][ni] = __builtin_amdgcn_mfma_f32_16x16x32_bf16(fa[mi], fbl[ni], acc[mi][ni], 0, 0, 0);
                acc[mi][ni] = __builtin_amdgcn_mfma_f32_16x16x32_bf16(fa[mi], fbh[ni], acc[mi][ni], 0, 0, 0);
            }
        __syncthreads();
    }

#pragma unroll
    for (int mi = 0; mi < 2; mi++)
#pragma unroll
        for (int ni = 0; ni < 4; ni++) {
            const int col = n0 + wc * 64 + ni * 16 + l15;
            const float bv = bias[col];
#pragma unroll
            for (int r = 0; r < 4; r++) {
                const int row = m0 + (wr * 2 + mi) * 16 + l4 * 4 + r;
                out1[(size_t)row * D_MODEL + col] = acc[mi][ni][r] + bv;
            }
        }
}

// ---------------- MFMA flash attention: swapped QK^T, in-register P, frag-linear LDS ----
// Block = 4 waves = one 64-query stripe p of one (b,h). 32-kpos tiles, double-buffered,
// __syncthreads()-drained staging (proven sync). All K/V LDS reads are base + lane*16
// (conflict-free frag-linear subtiles).
__global__ __launch_bounds__(256, 2) void attn_mfma(
    const unsigned short* __restrict__ Qh, const unsigned short* __restrict__ Ql,
    const unsigned short* __restrict__ Kh, const unsigned short* __restrict__ Kl,
    const unsigned short* __restrict__ VTh, const unsigned short* __restrict__ VTl,
    unsigned short* __restrict__ Aoh) {

    // LDS: 2 bufs x {Kh 4K | Kl 4K | VTh 4K | VTl 4K}
    __shared__ __align__(16) unsigned char LDS[32768];
    const int bx = blockIdx.x;
    const int bh = bx & 31;
    const int p = 31 - (bx >> 5);       // big stripes first
    const int tid = threadIdx.x;
    const int wq = tid >> 6, lane = tid & 63;
    const int b = bh >> 4, h = bh & 15;
    const int l15 = lane & 15, l4 = lane >> 4;

    // Q fragments (B-operand): lane l15 = q-col, k(d) = c*32 + l4*8 + j
    const int qbase = p * 64 + wq * 16;
    s8v fqh[2], fql[2];
    {
        const size_t rowB = ((size_t)bh * SEQ + qbase + l15) * 128;  // 128B per row
        const int kof = l4 * 16;
        fqh[0] = *(const s8v*)((const char*)Qh + rowB + kof);
        fqh[1] = *(const s8v*)((const char*)Qh + rowB + kof + 64);
        fql[0] = *(const s8v*)((const char*)Ql + rowB + kof);
        fql[1] = *(const s8v*)((const char*)Ql + rowB + kof + 64);
    }

    f4v oacc[4];  // O^T: [d = ni*16 + l4*4 + r][q = l15]
#pragma unroll
    for (int i = 0; i < 4; i++) oacc[i] = (f4v){0.f, 0.f, 0.f, 0.f};
    float m = -1e30f, l = 0.f;  // per-lane (q = l15); consistent across l4 copies

    const int nkt = 2 * (p + 1);  // 32-kpos tiles incl. diagonal

    // stage one 32-kpos tile (frag-linear subtiles; dest = base + lane*16)
    auto stage = [&](int t, unsigned char* bb) {
        {   // K hi/lo: subtile wq = (kt = wq>>1, dhalf = wq&1); lane block = (krow l15, dchunk l4)
            const int srow = (wq >> 1) * 16 + l15;
            const int doff = (wq & 1) * 64 + l4 * 16;  // byte offset in 128B row
            const size_t kB = ((size_t)bh * SEQ + (size_t)t * 32 + srow) * 128 + doff;
            gll16(bb + 0    + wq * 1024, (const char*)Kh + kB);
            gll16(bb + 4096 + wq * 1024, (const char*)Kl + kB);
        }
        {   // V^T hi/lo: subtile wq = d-rows wq*16..+16; lane block = (drow l15, kchunk l4)
            const int drow = wq * 16 + l15;
            const size_t vB = (((size_t)bh * 64 + drow) * SEQ + (size_t)t * 32 + l4 * 8) * 2;
            gll16(bb + 8192  + wq * 1024, (const char*)VTh + vB);
            gll16(bb + 12288 + wq * 1024, (const char*)VTl + vB);
        }
    };

    stage(0, LDS);

    for (int t = 0; t < nkt; ++t) {
        unsigned char* rb = (t & 1) ? (LDS + 16384) : LDS;
        __syncthreads();  // drains tile-t staging (vmcnt 0) + rendezvous
        if (t + 1 < nkt) stage(t + 1, (t & 1) ? LDS : (LDS + 16384));

        // ---- QK^T swapped (bf16x3): sacc[kt] = S^T[kpos = kt*16 + l4*4 + r][q = l15] ----
        f4v sacc[2];
#pragma unroll
        for (int kt = 0; kt < 2; kt++) sacc[kt] = (f4v){0.f, 0.f, 0.f, 0.f};
#pragma unroll
        for (int kt = 0; kt < 2; kt++) {
#pragma unroll
            for (int c = 0; c < 2; c++) {
                const int sb = ((kt * 2 + c) << 10) + lane * 16;
                s8v fkh = *(const s8v*)(rb + sb);
                s8v fkl = *(const s8v*)(rb + 4096 + sb);
                sacc[kt] = __builtin_amdgcn_mfma_f32_16x16x32_bf16(fkh, fql[c], sacc[kt], 0, 0, 0);
                sacc[kt] = __builtin_amdgcn_mfma_f32_16x16x32_bf16(fkl, fqh[c], sacc[kt], 0, 0, 0);
                sacc[kt] = __builtin_amdgcn_mfma_f32_16x16x32_bf16(fkh, fqh[c], sacc[kt], 0, 0, 0);
            }
        }

        // ---- lane-local online softmax (q = l15) ----
        const int dk0 = t * 32 - p * 64;        // tile kpos offset vs stripe base
        const int qlocal = wq * 16 + l15;
        float sv[8];
#pragma unroll
        for (int kt = 0; kt < 2; kt++)
#pragma unroll
            for (int r = 0; r < 4; r++) {
                const int kp = dk0 + kt * 16 + l4 * 4 + r;
                float s = sacc[kt][r] * 0.125f;
                sv[kt * 4 + r] = (kp > qlocal) ? -1e30f : s;
            }
        float pm = fmaxf(fmaxf(fmaxf(sv[0], sv[1]), fmaxf(sv[2], sv[3])),
                         fmaxf(fmaxf(sv[4], sv[5]), fmaxf(sv[6], sv[7])));
        pm = fmaxf(pm, __shfl_xor(pm, 16, 64));
        pm = fmaxf(pm, __shfl_xor(pm, 32, 64));
        const float mn = fmaxf(m, pm);
        const float cc = __expf(m - mn);
        m = mn;
        float ps[8], psum = 0.f;
#pragma unroll
        for (int i = 0; i < 8; i++) { ps[i] = __expf(sv[i] - mn); psum += ps[i]; }
        psum += __shfl_xor(psum, 16, 64);
        psum += __shfl_xor(psum, 32, 64);
        l = l * cc + psum;
#pragma unroll
        for (int ni = 0; ni < 4; ni++)
#pragma unroll
            for (int r = 0; r < 4; r++) oacc[ni][r] *= cc;

        // ---- build P^T B-frag in-register: lane needs P[kpos = l4*8 + j][q = l15] ----
        unsigned w0 = (unsigned)bf16_rne(ps[0]) | ((unsigned)bf16_rne(ps[1]) << 16);
        unsigned w1 = (unsigned)bf16_rne(ps[2]) | ((unsigned)bf16_rne(ps[3]) << 16);
        unsigned w2 = (unsigned)bf16_rne(ps[4]) | ((unsigned)bf16_rne(ps[5]) << 16);
        unsigned w3 = (unsigned)bf16_rne(ps[6]) | ((unsigned)bf16_rne(ps[7]) << 16);
        const bool lo2 = (l4 < 2);
        unsigned sA = lo2 ? w2 : w0, sB = lo2 ? w3 : w1;
        unsigned rA = (unsigned)__shfl_xor((int)sA, 32, 64);
        unsigned rB = (unsigned)__shfl_xor((int)sB, 32, 64);
        unsigned q0 = lo2 ? w0 : rA, q1 = lo2 ? w1 : rB;
        unsigned q2 = lo2 ? rA : w2, q3 = lo2 ? rB : w3;
        const bool ev = ((l4 & 1) == 0);
        unsigned sC = ev ? q2 : q0, sD = ev ? q3 : q1;
        unsigned rC = (unsigned)__shfl_xor((int)sC, 16, 64);
        unsigned rD = (unsigned)__shfl_xor((int)sD, 16, 64);
        unsigned d0 = ev ? q0 : rC, d1 = ev ? q1 : rD;
        unsigned d2 = ev ? rC : q2, d3 = ev ? rD : q3;
        s8v fp;
        ((unsigned*)&fp)[0] = d0; ((unsigned*)&fp)[1] = d1;
        ((unsigned*)&fp)[2] = d2; ((unsigned*)&fp)[3] = d3;

        // ---- PV: O^T[d][q] += V^T[d][kpos] * P^T[kpos][q]  (V hi+lo, P bf16) ----
#pragma unroll
        for (int ni = 0; ni < 4; ni++) {
            const int vb = (ni << 10) + lane * 16;
            s8v fvh = *(const s8v*)(rb + 8192 + vb);
            s8v fvl = *(const s8v*)(rb + 12288 + vb);
            oacc[ni] = __builtin_amdgcn_mfma_f32_16x16x32_bf16(fvl, fp, oacc[ni], 0, 0, 0);
            oacc[ni] = __builtin_amdgcn_mfma_f32_16x16x32_bf16(fvh, fp, oacc[ni], 0, 0, 0);
        }
    }

    // ---- epilogue: Aoh bf16 [b][s][h*64 + d], d = ni*16 + l4*4 + r ----
    const float inv = 1.0f / l;
    const int q = p * 64 + wq * 16 + l15;
    unsigned short* obase = Aoh + ((size_t)b * SEQ + q) * D_MODEL + h * DK;
#pragma unroll
    for (int ni = 0; ni < 4; ni++) {
        ushort4 o;
        o.x = bf16_rne(oacc[ni][0] * inv);
        o.y = bf16_rne(oacc[ni][1] * inv);
        o.z = bf16_rne(oacc[ni][2] * inv);
        o.w = bf16_rne(oacc[ni][3] * inv);
        *(ushort4*)(obase + ni * 16 + l4 * 4) = o;
    }
}

// ---------------------------------------------------------------------------
extern "C" void kernel_launch(void* const* d_in, const int* in_sizes, int n_in,
                              void* d_out, int out_size, void* d_ws, size_t ws_size,
                              hipStream_t stream) {
    const float* x  = (const float*)d_in[0];
    const float* Wq = (const float*)d_in[1];
    const float* bq = (const float*)d_in[2];
    const float* Wk = (const float*)d_in[3];
    const float* bk = (const float*)d_in[4];
    const float* Wv = (const float*)d_in[5];
    const float* bv = (const float*)d_in[6];
    const float* Wo = (const float*)d_in[7];
    const float* bo = (const float*)d_in[8];
    float* out = (float*)d_out;

    char* wsb = (char*)d_ws;  // footprint = 101,187,584 B (same as benched layout)
    unsigned short* xh  = (unsigned short*)(wsb);              // 8 MB: x cast bf16
    unsigned short* Aoh = (unsigned short*)(wsb + 8388608);    // 8 MB: attn out bf16
    unsigned short* wt  = (unsigned short*)(wsb + 16777216);   // W transposes (5 x 2MB used)
    unsigned short* Qh  = (unsigned short*)(wsb + 33554432);   // [bh][s][64] bf16, 8 MB each
    unsigned short* Ql  = (unsigned short*)(wsb + 41943040);
    unsigned short* Kh  = (unsigned short*)(wsb + 50331648);
    unsigned short* Kl  = (unsigned short*)(wsb + 58720256);
    unsigned short* Vh  = (unsigned short*)(wsb + 67108864);
    unsigned short* Vl  = (unsigned short*)(wsb + 75497472);
    unsigned short* VTh = (unsigned short*)(wsb + 83886080);   // [bh][64][s] bf16
    unsigned short* VTl = (unsigned short*)(wsb + 92274688);
    float* ct = (float*)(wsb + 100663296);
    float* st = (float*)(wsb + 100925440);

    const size_t WSZ = 1048576;

    rope_tab<<<256, 256, 0, stream>>>(ct, st);
    casth<<<1024, 256, 0, stream>>>(x, xh, (MROWS * D_MODEL) / 4);
    wtrans<<<dim3(16, 16), 256, 0, stream>>>(Wq, wt + 0 * WSZ);
    wtrans<<<dim3(16, 16), 256, 0, stream>>>(Wk, wt + 1 * WSZ);
    wtrans<<<dim3(16, 16), 256, 0, stream>>>(Wv, wt + 2 * WSZ);
    wsplit<<<dim3(16, 16), 256, 0, stream>>>(Wo, wt + 3 * WSZ, wt + 4 * WSZ);

    gemm_qkv<<<dim3(8, 32, 3), 256, 0, stream>>>(xh,
        wt + 0 * WSZ, wt + 1 * WSZ, wt + 2 * WSZ,
        bq, bk, bv, Qh, Ql, Kh, Kl, Vh, Vl, ct, st);

    vtrans<<<dim3(SEQ / 64, 32), 256, 0, stream>>>(Vh, VTh);
    vtrans<<<dim3(SEQ / 64, 32), 256, 0, stream>>>(Vl, VTl);

    attn_mfma<<<dim3(1024), 256, 0, stream>>>(Qh, Ql, Kh, Kl, VTh, VTl, Aoh);

    gemm_out<<<dim3(8, 64), 256, 0, stream>>>(Aoh, wt + 3 * WSZ, wt + 4 * WSZ, bo, out);
}